// Round 5
// baseline (7828.038 us; speedup 1.0000x reference)
//
#include <hip/hip_runtime.h>
#include <math.h>

// Problem constants (fixed by the reference)
#define HDIM   512
#define NDIM   16
#define SEQ    64
#define TSTEPS 63
#define BATCH  256
#define ODIM   9
#define NTHR   1024

// R12: zero-communication design (R11, confirmed: removing inter-WG exchange
// cut FETCH 4.2GB->423MB) with the two R11 gaps fixed:
//  1) 1024 thr/WG -> 16 waves/CU (was 8): doubles latency hiding for the
//     64-load/thread weight stream (R11: VALUBusy 25%, occ 24% -> latency-bound).
//  2) Per-WG row sweep decorrelation (R7 had it, R11 dropped it): row-group
//     permutation (rg+b)&7 + rotated start within each 64-row window, so the
//     256 CUs don't camp on the same L2 lines in lockstep.
// One WG = one batch, full 512x512 matvec per WG per blk-step from L2
// (weights 2MB, L2-resident per XCD). No mailbox/flags/spins: no hang class.
// blk0 A/B/C in VGPRs, blk1 A/B/C in LDS (96KB); ~120KB LDS total, 1 WG/CU
// (grid==CU count anyway). S4 n-reduce: fold-exchange, 3 stages + butterfly,
// lane n<8 holds h = hgg + 64n. Per-column phases gated tid<512; ALL
// __syncthreads unconditional.

typedef float f32x4 __attribute__((ext_vector_type(4)));

__device__ __forceinline__ float gelu_f32(float x) {
    return 0.5f * x * (1.0f + erff(x * 0.70710678118654752440f));
}

__device__ __forceinline__ float sig32(float x) {
    return 1.0f / (1.0f + expf(-x));
}

__device__ __forceinline__ void fma_row4(float4& acc, const float4 g,
                                         const float4 w0, const float4 w1,
                                         const float4 w2, const float4 w3) {
    acc.x = fmaf(g.w, w3.x, fmaf(g.z, w2.x, fmaf(g.y, w1.x, fmaf(g.x, w0.x, acc.x))));
    acc.y = fmaf(g.w, w3.y, fmaf(g.z, w2.y, fmaf(g.y, w1.y, fmaf(g.x, w0.y, acc.y))));
    acc.z = fmaf(g.w, w3.z, fmaf(g.z, w2.z, fmaf(g.y, w1.z, fmaf(g.x, w0.z, acc.z))));
    acc.w = fmaf(g.w, w3.w, fmaf(g.z, w2.w, fmaf(g.y, w1.w, fmaf(g.x, w0.w, acc.w))));
}

__global__ __launch_bounds__(NTHR, 1)
void s4_decode_kernel(
    const float* __restrict__ input_seq,   // (B,S,3)
    const float* __restrict__ in_W,        // (3,H)
    const float* __restrict__ in_b,        // (H)
    const float* __restrict__ Aarr,        // (L,H,N)
    const float* __restrict__ Barr,        // (L,H,N)
    const float* __restrict__ Carr,        // (L,H,N)
    const float* __restrict__ Darr,        // (L,H)
    const float* __restrict__ outW,        // (L,H,H)
    const float* __restrict__ outb,        // (L,H)
    const float* __restrict__ ln_g,        // (L,H)
    const float* __restrict__ ln_b,        // (L,H)
    const float* __restrict__ headW,       // (H,9)
    const float* __restrict__ headb,       // (9)
    float* __restrict__ out)               // (B,T,9)
{
    __shared__ __align__(16) float ld_x[HDIM];          // block input (dp or xn)
    __shared__ __align__(16) float ld_g[HDIM];          // gelu output
    __shared__ __align__(16) float4 ld_z4[8 * 128];     // 16 KB matvec partials
    __shared__ __align__(16) float ld_A1[HDIM * NDIM];  // 32 KB blk1 params
    __shared__ __align__(16) float ld_B1[HDIM * NDIM];  // 32 KB
    __shared__ __align__(16) float ld_C1[HDIM * NDIM];  // 32 KB
    __shared__ float ld_D0[HDIM];
    __shared__ float ld_D1[HDIM];
    __shared__ float ld_red[32];                        // LN partials (8 used)
    __shared__ float ld_hred[8 * ODIM];                 // head partials (waves 0-7)
    __shared__ float ld_logit[ODIM + 1];
    __shared__ float ld_dec[4];
    __shared__ int   ld_ptr;

    const int b   = blockIdx.x;
    const int tid = threadIdx.x;
    const int n   = tid & 15;               // state n-index
    const int hgg = tid >> 4;               // [0,64) h sub-position
    const int col = tid & (HDIM - 1);       // column for per-col phases

    // ---- stage blk1 A/B/C + D into LDS (one-time) ----
    for (int idx = tid; idx < HDIM * NDIM; idx += NTHR) {
        ld_A1[idx] = Aarr[HDIM * NDIM + idx];
        ld_B1[idx] = Barr[HDIM * NDIM + idx];
        ld_C1[idx] = Carr[HDIM * NDIM + idx];
    }
    if (tid < HDIM) {
        ld_D0[tid] = Darr[tid];
        ld_D1[tid] = Darr[HDIM + tid];
    }

    // ---- persistent: blk0 params + both blk states in registers ----
    float s0[8], s1[8];
    float A0[8], B0[8], C0[8];
    #pragma unroll
    for (int k = 0; k < 8; ++k) {
        const int h  = hgg + 64 * k;
        const int i0 = h * NDIM + n;
        A0[k] = Aarr[i0]; B0[k] = Barr[i0]; C0[k] = Carr[i0];
        s0[k] = 0.f; s1[k] = 0.f;
    }

    // per-column constants (duplicated in tid>=512, harmless)
    const float inb_t = in_b[col];
    const float w0 = in_W[col], w1 = in_W[HDIM + col], w2 = in_W[2 * HDIM + col];
    const float ob0 = outb[col], ob1 = outb[HDIM + col];
    const float lg0 = ln_g[col], lg1 = ln_g[HDIM + col];
    const float lb0 = ln_b[col], lb1 = ln_b[HDIM + col];
    float hw[ODIM];
    #pragma unroll
    for (int o = 0; o < ODIM; ++o) hw[o] = headW[col * ODIM + o];

    float ctx = 0.f;
    if (tid == 0) { ld_dec[0] = 0.f; ld_dec[1] = 0.f; ld_dec[2] = 1.f; }
    __syncthreads();

    for (int i = 0; i < TSTEPS; ++i) {
        // ---- decoder input projection ----
        const float dpv = fmaf(ld_dec[0], w0,
                          fmaf(ld_dec[1], w1,
                          fmaf(ld_dec[2], w2, inb_t)));
        __syncthreads();                    // ld_dec consumed
        if (tid < HDIM) ld_x[tid] = dpv;
        __syncthreads();

        float xn = 0.f;

        #pragma unroll
        for (int blk = 0; blk < 2; ++blk) {
            // ---- S4 state update + C*s partials (all 1024 threads, 8 each) ----
            float p[8];
            if (blk == 0) {
                #pragma unroll
                for (int k = 0; k < 8; ++k) {
                    const float x  = ld_x[hgg + 64 * k];
                    const float sv = fmaf(A0[k], s0[k], B0[k] * x);
                    s0[k] = sv;
                    p[k] = sv * C0[k];
                }
            } else {
                #pragma unroll
                for (int k = 0; k < 8; ++k) {
                    const int ia = (hgg + 64 * k) * NDIM + n;
                    const float x  = ld_x[hgg + 64 * k];
                    const float sv = fmaf(ld_A1[ia], s1[k], ld_B1[ia] * x);
                    s1[k] = sv;
                    p[k] = sv * ld_C1[ia];
                }
            }
            // ---- fold-exchange reduce over n (16 lanes, 8 values):
            //      3 fold stages + final butterfly; lane n<8 holds value n
            {
                float q4[4];
                { const bool bt = (n & 1) != 0;
                  #pragma unroll
                  for (int u = 0; u < 4; ++u) {
                      const float sd = bt ? p[2 * u] : p[2 * u + 1];
                      const float rc = __shfl_xor(sd, 1);
                      q4[u] = (bt ? p[2 * u + 1] : p[2 * u]) + rc;
                  } }
                float q2[2];
                { const bool bt = (n & 2) != 0;
                  #pragma unroll
                  for (int u = 0; u < 2; ++u) {
                      const float sd = bt ? q4[2 * u] : q4[2 * u + 1];
                      const float rc = __shfl_xor(sd, 2);
                      q2[u] = (bt ? q4[2 * u + 1] : q4[2 * u]) + rc;
                  } }
                float y;
                { const bool bt = (n & 4) != 0;
                  const float sd = bt ? q2[0] : q2[1];
                  const float rc = __shfl_xor(sd, 4);
                  y = (bt ? q2[1] : q2[0]) + rc; }
                y += __shfl_xor(y, 8);      // full sum over 16 n; lane n holds k=n&7
                if ((n & 8) == 0) {         // lanes n=0..7 write h = hgg + 64n
                    const int h2 = hgg + 64 * n;
                    const float dd = blk ? ld_D1[h2] : ld_D0[h2];
                    ld_g[h2] = gelu_f32(fmaf(dd, ld_x[h2], y));
                }
            }
            __syncthreads();

            // ---- full matvec: 512x512, rows split 8 ways, decorrelated sweep ----
            {
                const int rg   = tid >> 7;              // row group [0,8)
                const int c    = tid & 127;             // float4 output column
                const int rge  = (rg + b) & 7;          // per-WG group permutation
                const int rowbase = rge * 64;
                const int roff = (b & 15) * 4;          // rotated start, mult of 4
                const float4* Wb = (const float4*)outW
                    + (((size_t)blk) << 16) + (size_t)rowbase * 128 + c;
                float4 acc = make_float4(0.f, 0.f, 0.f, 0.f);
                int q = roff;
                float4 a0 = Wb[(size_t)(q + 0) * 128], a1 = Wb[(size_t)(q + 1) * 128],
                       a2 = Wb[(size_t)(q + 2) * 128], a3 = Wb[(size_t)(q + 3) * 128];
                #pragma unroll
                for (int ch = 0; ch < 16; ++ch) {
                    float4 b0, b1, b2, b3;
                    const int qn = (roff + 4 * ch + 4) & 63;
                    if (ch < 15) {
                        b0 = Wb[(size_t)(qn + 0) * 128]; b1 = Wb[(size_t)(qn + 1) * 128];
                        b2 = Wb[(size_t)(qn + 2) * 128]; b3 = Wb[(size_t)(qn + 3) * 128];
                    }
                    const float4 g4 = *(const float4*)&ld_g[rowbase + q];
                    fma_row4(acc, g4, a0, a1, a2, a3);
                    if (ch < 15) { a0 = b0; a1 = b1; a2 = b2; a3 = b3; q = qn; }
                }
                ld_z4[rg * 128 + c] = acc;
            }
            __syncthreads();

            // ---- combine 8 row-group partials + residual + one-pass LN ----
            float tmp = 0.f;
            if (tid < HDIM) {
                const float* zf = (const float*)ld_z4;
                float z = blk ? ob1 : ob0;
                #pragma unroll
                for (int q = 0; q < 8; ++q) z += zf[q * HDIM + tid];
                const float res = (i == 0) ? dpv : z;   // ref: residual=proj @ i==0
                tmp = z + res;
            }
            {
                float v1 = tmp, v2 = tmp * tmp;
                if (tid < HDIM) {                       // waves 8-15 skip (uniform)
                    #pragma unroll
                    for (int m = 1; m < 64; m <<= 1) {
                        v1 += __shfl_xor(v1, m);
                        v2 += __shfl_xor(v2, m);
                    }
                    if ((tid & 63) == 0) {
                        ld_red[2 * (tid >> 6)]     = v1;
                        ld_red[2 * (tid >> 6) + 1] = v2;
                    }
                }
                __syncthreads();
                if (tid < HDIM) {
                    float s1r = 0.f, s2r = 0.f;
                    #pragma unroll
                    for (int q = 0; q < 8; ++q) { s1r += ld_red[2 * q]; s2r += ld_red[2 * q + 1]; }
                    const float mu  = s1r * (1.f / 512.f);
                    const float var = s2r * (1.f / 512.f) - mu * mu;
                    const float rs  = rsqrtf(var + 1e-5f);
                    xn = (tmp - mu) * rs * (blk ? lg1 : lg0) + (blk ? lb1 : lb0);
                }
                if (blk == 0) {
                    if (tid < HDIM) ld_x[tid] = xn;     // old ld_x reads all pre-g-barrier
                    __syncthreads();
                }
            }
        } // blk

        // ================= head #1 =================
        {
            float hp[ODIM];
            #pragma unroll
            for (int o = 0; o < ODIM; ++o) hp[o] = 0.f;
            if (tid < HDIM) {
                const float v = xn + ctx;
                #pragma unroll
                for (int o = 0; o < ODIM; ++o) hp[o] = v * hw[o];
                #pragma unroll
                for (int m = 1; m < 64; m <<= 1) {
                    #pragma unroll
                    for (int o = 0; o < ODIM; ++o) hp[o] += __shfl_xor(hp[o], m);
                }
                if ((tid & 63) == 0) {
                    const int wv = tid >> 6;
                    #pragma unroll
                    for (int o = 0; o < ODIM; ++o) ld_hred[wv * ODIM + o] = hp[o];
                }
            }
            __syncthreads();
            if (tid < ODIM) {
                float s = headb[tid];
                #pragma unroll
                for (int wv = 0; wv < 8; ++wv) s += ld_hred[wv * ODIM + tid];
                ld_logit[tid] = s;
            }
            __syncthreads();
        }

        const bool is_out = ((i & 1) == 0);
        if (is_out) {
            if (tid < ODIM)
                out[((size_t)b * TSTEPS + i) * ODIM + tid] = sig32(ld_logit[tid]);
            if (tid == 0) {
                const float nc = (sig32(ld_logit[0]) > 0.5f) ? 1.f : 0.f;
                ld_dec[0] = nc; ld_dec[1] = 1.f; ld_dec[2] = 0.f;
            }
            __syncthreads();
        } else {
            // np.argmax over f32 SIGMOIDS (saturation => not logit-argmax!)
            if (tid == 0) {
                int best = 0; float bv = sig32(ld_logit[3]);
                #pragma unroll
                for (int o = 1; o < 6; ++o) {
                    const float v2 = sig32(ld_logit[3 + o]);
                    if (v2 > bv) { bv = v2; best = o; }
                }
                ld_ptr = best;
                ld_dec[0] = 0.f; ld_dec[1] = 0.f; ld_dec[2] = 1.f;
            }
            __syncthreads();
            {   // ctx += encoded[b, ptr, :] at own column
                const float* iseq = input_seq + ((size_t)b * SEQ + ld_ptr) * 3;
                ctx += fmaf(iseq[0], w0, fmaf(iseq[1], w1, fmaf(iseq[2], w2, inb_t)));
            }
            __syncthreads();
            // ================= head #2 (post-ctx-update) =================
            {
                float hq[ODIM];
                #pragma unroll
                for (int o = 0; o < ODIM; ++o) hq[o] = 0.f;
                if (tid < HDIM) {
                    const float v = xn + ctx;
                    #pragma unroll
                    for (int o = 0; o < ODIM; ++o) hq[o] = v * hw[o];
                    #pragma unroll
                    for (int m = 1; m < 64; m <<= 1) {
                        #pragma unroll
                        for (int o = 0; o < ODIM; ++o) hq[o] += __shfl_xor(hq[o], m);
                    }
                    if ((tid & 63) == 0) {
                        const int wv = tid >> 6;
                        #pragma unroll
                        for (int o = 0; o < ODIM; ++o) ld_hred[wv * ODIM + o] = hq[o];
                    }
                }
                __syncthreads();
                if (tid < ODIM) {
                    float s = headb[tid];
                    #pragma unroll
                    for (int wv = 0; wv < 8; ++wv) s += ld_hred[wv * ODIM + tid];
                    out[((size_t)b * TSTEPS + i) * ODIM + tid] = sig32(s);
                }
                __syncthreads();
            }
        }
    }
}

extern "C" void kernel_launch(void* const* d_in, const int* in_sizes, int n_in,
                              void* d_out, int out_size, void* d_ws, size_t ws_size,
                              hipStream_t stream) {
    (void)in_sizes; (void)n_in; (void)d_ws; (void)ws_size; (void)out_size;
    const float* input_seq = (const float*)d_in[0];
    // d_in[1] = autoregressive_steps (scalar) -- T fixed at 63 by the model
    const float* in_W   = (const float*)d_in[2];
    const float* in_b   = (const float*)d_in[3];
    const float* Aarr   = (const float*)d_in[4];
    const float* Barr   = (const float*)d_in[5];
    const float* Carr   = (const float*)d_in[6];
    const float* Darr   = (const float*)d_in[7];
    const float* outW   = (const float*)d_in[8];
    const float* outb   = (const float*)d_in[9];
    const float* ln_g   = (const float*)d_in[10];
    const float* ln_b   = (const float*)d_in[11];
    const float* headW  = (const float*)d_in[12];
    const float* headb  = (const float*)d_in[13];
    float* out = (float*)d_out;

    // No workspace use: zero inter-WG communication in this design.
    s4_decode_kernel<<<BATCH, NTHR, 0, stream>>>(
        input_seq, in_W, in_b, Aarr, Barr, Carr, Darr,
        outW, outb, ln_g, ln_b, headW, headb, out);
}

// Round 6
// 2908.343 us; speedup vs baseline: 2.6916x; 2.6916x over previous
//
#include <hip/hip_runtime.h>
#include <math.h>

// Problem constants (fixed by the reference)
#define HDIM   512
#define NDIM   16
#define SEQ    64
#define TSTEPS 63
#define BATCH  256
#define ODIM   9
#define NTHR   512
#define NWG    128   // 2 batches per WG

// R13: zero-communication (R11 lineage; R11 confirmed FETCH 423MB clean) with
// 2-batch weight reuse per WG. R11 datum: 1MB/blk-step weight stream =
// ~14.9us/blk-step => ~70GB/s/CU effective; serving ONE batch. R13 streams
// the same bytes for TWO batches (8 FMA per 16B load, half the WGs =>
// half the per-XCD L2 demand). Helps both candidate regimes (contention:
// per-CU BW ~2x; latency: more FMA under the stall shadow).
// R12 lesson: 1024 thr => VGPR cap 64 => spill catastrophe. Stay at 512 thr.
// R9/R10 lesson: sc0 mailbox gathers miss L2 when the XCD handshake fails
// (container-dependent blockIdx->XCD mapping) -> avoid all inter-WG comm.
// blk0 A/B/C in VGPRs (48), blk1 A/B/C in LDS (96KB). States 64 VGPRs.
// All batch/k loops fully unrolled with named arrays (rule #20).

typedef float f32x4 __attribute__((ext_vector_type(4)));

__device__ __forceinline__ float gelu_f32(float x) {
    return 0.5f * x * (1.0f + erff(x * 0.70710678118654752440f));
}

__device__ __forceinline__ float sig32(float x) {
    return 1.0f / (1.0f + expf(-x));
}

__device__ __forceinline__ void fma_row4(float4& acc, const float4 g,
                                         const float4 w0, const float4 w1,
                                         const float4 w2, const float4 w3) {
    acc.x = fmaf(g.w, w3.x, fmaf(g.z, w2.x, fmaf(g.y, w1.x, fmaf(g.x, w0.x, acc.x))));
    acc.y = fmaf(g.w, w3.y, fmaf(g.z, w2.y, fmaf(g.y, w1.y, fmaf(g.x, w0.y, acc.y))));
    acc.z = fmaf(g.w, w3.z, fmaf(g.z, w2.z, fmaf(g.y, w1.z, fmaf(g.x, w0.z, acc.z))));
    acc.w = fmaf(g.w, w3.w, fmaf(g.z, w2.w, fmaf(g.y, w1.w, fmaf(g.x, w0.w, acc.w))));
}

// fold-exchange reduce over n (16 lanes, 16 values): lane n ends holding the
// full 16-lane sum of value v == n. Validated (passed) in R9/R10 runs.
#define FOLD16(P, YOUT)                                                        \
    {                                                                          \
        float q8[8];                                                           \
        { const bool bt = (n & 1) != 0;                                        \
          _Pragma("unroll")                                                    \
          for (int u = 0; u < 8; ++u) {                                        \
              const float sd = bt ? P[2 * u] : P[2 * u + 1];                   \
              const float rc = __shfl_xor(sd, 1);                              \
              q8[u] = (bt ? P[2 * u + 1] : P[2 * u]) + rc;                     \
          } }                                                                  \
        float q4[4];                                                           \
        { const bool bt = (n & 2) != 0;                                        \
          _Pragma("unroll")                                                    \
          for (int u = 0; u < 4; ++u) {                                        \
              const float sd = bt ? q8[2 * u] : q8[2 * u + 1];                 \
              const float rc = __shfl_xor(sd, 2);                              \
              q4[u] = (bt ? q8[2 * u + 1] : q8[2 * u]) + rc;                   \
          } }                                                                  \
        float q2[2];                                                           \
        { const bool bt = (n & 4) != 0;                                        \
          _Pragma("unroll")                                                    \
          for (int u = 0; u < 2; ++u) {                                        \
              const float sd = bt ? q4[2 * u] : q4[2 * u + 1];                 \
              const float rc = __shfl_xor(sd, 4);                              \
              q2[u] = (bt ? q4[2 * u + 1] : q4[2 * u]) + rc;                   \
          } }                                                                  \
        { const bool bt = (n & 8) != 0;                                        \
          const float sd = bt ? q2[0] : q2[1];                                 \
          const float rc = __shfl_xor(sd, 8);                                  \
          YOUT = (bt ? q2[1] : q2[0]) + rc; }                                  \
    }

__global__ __launch_bounds__(NTHR, 1)
void s4_decode_kernel(
    const float* __restrict__ input_seq,   // (B,S,3)
    const float* __restrict__ in_W,        // (3,H)
    const float* __restrict__ in_b,        // (H)
    const float* __restrict__ Aarr,        // (L,H,N)
    const float* __restrict__ Barr,        // (L,H,N)
    const float* __restrict__ Carr,        // (L,H,N)
    const float* __restrict__ Darr,        // (L,H)
    const float* __restrict__ outW,        // (L,H,H)
    const float* __restrict__ outb,        // (L,H)
    const float* __restrict__ ln_g,        // (L,H)
    const float* __restrict__ ln_b,        // (L,H)
    const float* __restrict__ headW,       // (H,9)
    const float* __restrict__ headb,       // (9)
    float* __restrict__ out)               // (B,T,9)
{
    __shared__ __align__(16) float ld_x[2 * HDIM];      // block input, 2 batches
    __shared__ __align__(16) float ld_g[2 * HDIM];      // gelu out, 2 batches
    __shared__ __align__(16) float4 ld_z4[8 * 128];     // 16 KB matvec partials
    __shared__ __align__(16) float ld_A1[HDIM * NDIM];  // 32 KB blk1 params
    __shared__ __align__(16) float ld_B1[HDIM * NDIM];  // 32 KB
    __shared__ __align__(16) float ld_C1[HDIM * NDIM];  // 32 KB
    __shared__ float ld_D0[HDIM];
    __shared__ float ld_D1[HDIM];
    __shared__ float ld_red[32];                        // LN partials: 8 waves x 4
    __shared__ float ld_hred[8 * 2 * ODIM];             // head partials
    __shared__ float ld_logit[2 * ODIM];
    __shared__ float ld_dec[8];                         // 2 batches x {c0,c1,c2,pad}
    __shared__ int   ld_ptr[2];

    const int b   = blockIdx.x;            // WG id: batches 2b, 2b+1
    const int tid = threadIdx.x;
    const int n   = tid & 15;              // state n-index
    const int hg  = tid >> 4;              // [0,32) h sub-position

    // ---- stage blk1 A/B/C + D into LDS (one-time) ----
    for (int idx = tid; idx < HDIM * NDIM; idx += NTHR) {
        ld_A1[idx] = Aarr[HDIM * NDIM + idx];
        ld_B1[idx] = Barr[HDIM * NDIM + idx];
        ld_C1[idx] = Carr[HDIM * NDIM + idx];
    }
    ld_D0[tid] = Darr[tid];
    ld_D1[tid] = Darr[HDIM + tid];

    // ---- persistent: blk0 params (batch-shared) + states for 2 batches ----
    float A0[16], B0[16], C0[16];
    float s0a[16], s0b[16], s1a[16], s1b[16];   // blk{0,1} x batch{a,b}
    #pragma unroll
    for (int k = 0; k < 16; ++k) {
        const int i0 = (hg + 32 * k) * NDIM + n;
        A0[k] = Aarr[i0]; B0[k] = Barr[i0]; C0[k] = Carr[i0];
        s0a[k] = 0.f; s0b[k] = 0.f; s1a[k] = 0.f; s1b[k] = 0.f;
    }

    // per-column constants
    const float inb_t = in_b[tid];
    const float w0 = in_W[tid], w1 = in_W[HDIM + tid], w2 = in_W[2 * HDIM + tid];
    const float ob0 = outb[tid], ob1 = outb[HDIM + tid];
    const float lg0 = ln_g[tid], lg1 = ln_g[HDIM + tid];
    const float lb0 = ln_b[tid], lb1 = ln_b[HDIM + tid];
    float hw[ODIM];
    #pragma unroll
    for (int o = 0; o < ODIM; ++o) hw[o] = headW[tid * ODIM + o];

    float ctxa = 0.f, ctxb = 0.f;
    if (tid < 2) { ld_dec[4 * tid] = 0.f; ld_dec[4 * tid + 1] = 0.f; ld_dec[4 * tid + 2] = 1.f; }
    __syncthreads();

    for (int i = 0; i < TSTEPS; ++i) {
        // ---- decoder input projection, both batches, at own column ----
        const float dpa = fmaf(ld_dec[0], w0, fmaf(ld_dec[1], w1, fmaf(ld_dec[2], w2, inb_t)));
        const float dpb = fmaf(ld_dec[4], w0, fmaf(ld_dec[5], w1, fmaf(ld_dec[6], w2, inb_t)));
        __syncthreads();                    // ld_dec consumed
        ld_x[tid] = dpa;
        ld_x[HDIM + tid] = dpb;
        __syncthreads();

        float xna = 0.f, xnb = 0.f;

        #pragma unroll
        for (int blk = 0; blk < 2; ++blk) {
            // ---- S4 state update + C*s partials, both batches ----
            float pa[16], pb[16];
            if (blk == 0) {
                #pragma unroll
                for (int k = 0; k < 16; ++k) {
                    const int h = hg + 32 * k;
                    const float xa = ld_x[h], xb = ld_x[HDIM + h];
                    const float sva = fmaf(A0[k], s0a[k], B0[k] * xa);
                    const float svb = fmaf(A0[k], s0b[k], B0[k] * xb);
                    s0a[k] = sva; s0b[k] = svb;
                    pa[k] = sva * C0[k];
                    pb[k] = svb * C0[k];
                }
            } else {
                #pragma unroll
                for (int k = 0; k < 16; ++k) {
                    const int h = hg + 32 * k;
                    const int ia = h * NDIM + n;
                    const float Ak = ld_A1[ia], Bk = ld_B1[ia], Ck = ld_C1[ia];
                    const float xa = ld_x[h], xb = ld_x[HDIM + h];
                    const float sva = fmaf(Ak, s1a[k], Bk * xa);
                    const float svb = fmaf(Ak, s1b[k], Bk * xb);
                    s1a[k] = sva; s1b[k] = svb;
                    pa[k] = sva * Ck;
                    pb[k] = svb * Ck;
                }
            }
            // ---- fold-exchange per batch; lane n writes h2 = hg + 32n ----
            {
                float ya, yb;
                FOLD16(pa, ya);
                FOLD16(pb, yb);
                const int h2 = hg + 32 * n;
                const float dd = blk ? ld_D1[h2] : ld_D0[h2];
                ld_g[h2]        = gelu_f32(fmaf(dd, ld_x[h2], ya));
                ld_g[HDIM + h2] = gelu_f32(fmaf(dd, ld_x[HDIM + h2], yb));
            }
            __syncthreads();

            // ---- matvec: 512 rows x 512 outputs x 2 batches, rows 4-way split ----
            {
                const int rg = tid >> 7;            // row quarter [0,4)
                const int c  = tid & 127;           // float4 output column
                const float4* Wb = (const float4*)outW
                    + (((size_t)blk) << 16) + (size_t)(rg * 128) * 128 + c;
                const float* gqa = &ld_g[rg * 128];
                const float* gqb = &ld_g[HDIM + rg * 128];
                float4 acca = make_float4(0.f, 0.f, 0.f, 0.f);
                float4 accb = make_float4(0.f, 0.f, 0.f, 0.f);
                float4 a0 = Wb[0 * 128], a1 = Wb[1 * 128],
                       a2 = Wb[2 * 128], a3 = Wb[3 * 128];
                #pragma unroll 2
                for (int rr = 0; rr < 128; rr += 4) {
                    float4 b0, b1, b2, b3;
                    if (rr < 124) {
                        b0 = Wb[(size_t)(rr + 4) * 128];
                        b1 = Wb[(size_t)(rr + 5) * 128];
                        b2 = Wb[(size_t)(rr + 6) * 128];
                        b3 = Wb[(size_t)(rr + 7) * 128];
                    }
                    const float4 g4a = *(const float4*)&gqa[rr];
                    const float4 g4b = *(const float4*)&gqb[rr];
                    fma_row4(acca, g4a, a0, a1, a2, a3);
                    fma_row4(accb, g4b, a0, a1, a2, a3);
                    if (rr < 124) { a0 = b0; a1 = b1; a2 = b2; a3 = b3; }
                }
                ld_z4[(0 * 4 + rg) * 128 + c] = acca;
                ld_z4[(1 * 4 + rg) * 128 + c] = accb;
            }
            __syncthreads();

            // ---- combine 4 row-quarter partials + residual + one-pass LN ----
            {
                const float* zf = (const float*)ld_z4;
                const float ob = blk ? ob1 : ob0;
                const float za = zf[0 * HDIM + tid] + zf[1 * HDIM + tid]
                               + zf[2 * HDIM + tid] + zf[3 * HDIM + tid] + ob;
                const float zb = zf[4 * HDIM + tid] + zf[5 * HDIM + tid]
                               + zf[6 * HDIM + tid] + zf[7 * HDIM + tid] + ob;
                const float ra = (i == 0) ? dpa : za;   // ref: residual=proj @ i==0
                const float rb = (i == 0) ? dpb : zb;
                const float ta = za + ra;
                const float tb = zb + rb;
                float v1a = ta, v2a = ta * ta, v1b = tb, v2b = tb * tb;
                #pragma unroll
                for (int m = 1; m < 64; m <<= 1) {
                    v1a += __shfl_xor(v1a, m);
                    v2a += __shfl_xor(v2a, m);
                    v1b += __shfl_xor(v1b, m);
                    v2b += __shfl_xor(v2b, m);
                }
                if ((tid & 63) == 0) {
                    const int wv = tid >> 6;
                    ld_red[wv * 4 + 0] = v1a; ld_red[wv * 4 + 1] = v2a;
                    ld_red[wv * 4 + 2] = v1b; ld_red[wv * 4 + 3] = v2b;
                }
                __syncthreads();
                float s1ra = 0.f, s2ra = 0.f, s1rb = 0.f, s2rb = 0.f;
                #pragma unroll
                for (int q = 0; q < 8; ++q) {
                    s1ra += ld_red[q * 4 + 0]; s2ra += ld_red[q * 4 + 1];
                    s1rb += ld_red[q * 4 + 2]; s2rb += ld_red[q * 4 + 3];
                }
                const float glG = blk ? lg1 : lg0;
                const float glB = blk ? lb1 : lb0;
                {
                    const float mu  = s1ra * (1.f / 512.f);
                    const float var = s2ra * (1.f / 512.f) - mu * mu;
                    xna = (ta - mu) * rsqrtf(var + 1e-5f) * glG + glB;
                }
                {
                    const float mu  = s1rb * (1.f / 512.f);
                    const float var = s2rb * (1.f / 512.f) - mu * mu;
                    xnb = (tb - mu) * rsqrtf(var + 1e-5f) * glG + glB;
                }
                if (blk == 0) {
                    __syncthreads();        // ld_red consumed before rewrite next blk
                    ld_x[tid] = xna;
                    ld_x[HDIM + tid] = xnb;
                    __syncthreads();
                }
            }
        } // blk

        // ================= head #1 (both batches) =================
        {
            const float va = xna + ctxa;
            const float vb = xnb + ctxb;
            float hpa[ODIM], hpb[ODIM];
            #pragma unroll
            for (int o = 0; o < ODIM; ++o) { hpa[o] = va * hw[o]; hpb[o] = vb * hw[o]; }
            #pragma unroll
            for (int m = 1; m < 64; m <<= 1) {
                #pragma unroll
                for (int o = 0; o < ODIM; ++o) {
                    hpa[o] += __shfl_xor(hpa[o], m);
                    hpb[o] += __shfl_xor(hpb[o], m);
                }
            }
            if ((tid & 63) == 0) {
                const int wv = tid >> 6;
                #pragma unroll
                for (int o = 0; o < ODIM; ++o) {
                    ld_hred[wv * 18 + o]        = hpa[o];
                    ld_hred[wv * 18 + ODIM + o] = hpb[o];
                }
            }
            __syncthreads();
            if (tid < 18) {
                float s = headb[tid % ODIM];
                #pragma unroll
                for (int wv = 0; wv < 8; ++wv) s += ld_hred[wv * 18 + tid];
                ld_logit[tid] = s;
            }
            __syncthreads();
        }

        const bool is_out = ((i & 1) == 0);
        if (is_out) {
            if (tid < 18) {
                const int j = tid / ODIM, o = tid - j * ODIM;
                out[((size_t)(2 * b + j) * TSTEPS + i) * ODIM + o] = sig32(ld_logit[tid]);
            }
            if (tid < 2) {
                const float nc = (sig32(ld_logit[tid * ODIM]) > 0.5f) ? 1.f : 0.f;
                ld_dec[4 * tid] = nc; ld_dec[4 * tid + 1] = 1.f; ld_dec[4 * tid + 2] = 0.f;
            }
            __syncthreads();
        } else {
            // np.argmax over f32 SIGMOIDS (saturation => not logit-argmax!)
            if (tid < 2) {
                const int base9 = tid * ODIM;
                int best = 0; float bv = sig32(ld_logit[base9 + 3]);
                #pragma unroll
                for (int o = 1; o < 6; ++o) {
                    const float v2 = sig32(ld_logit[base9 + 3 + o]);
                    if (v2 > bv) { bv = v2; best = o; }
                }
                ld_ptr[tid] = best;
                ld_dec[4 * tid] = 0.f; ld_dec[4 * tid + 1] = 0.f; ld_dec[4 * tid + 2] = 1.f;
            }
            __syncthreads();
            {   // ctx[j] += encoded[batch_j, ptr_j, :] at own column
                const float* ia = input_seq + ((size_t)(2 * b + 0) * SEQ + ld_ptr[0]) * 3;
                const float* ib = input_seq + ((size_t)(2 * b + 1) * SEQ + ld_ptr[1]) * 3;
                ctxa += fmaf(ia[0], w0, fmaf(ia[1], w1, fmaf(ia[2], w2, inb_t)));
                ctxb += fmaf(ib[0], w0, fmaf(ib[1], w1, fmaf(ib[2], w2, inb_t)));
            }
            __syncthreads();
            // ================= head #2 (post-ctx-update) =================
            {
                const float va = xna + ctxa;
                const float vb = xnb + ctxb;
                float hqa[ODIM], hqb[ODIM];
                #pragma unroll
                for (int o = 0; o < ODIM; ++o) { hqa[o] = va * hw[o]; hqb[o] = vb * hw[o]; }
                #pragma unroll
                for (int m = 1; m < 64; m <<= 1) {
                    #pragma unroll
                    for (int o = 0; o < ODIM; ++o) {
                        hqa[o] += __shfl_xor(hqa[o], m);
                        hqb[o] += __shfl_xor(hqb[o], m);
                    }
                }
                if ((tid & 63) == 0) {
                    const int wv = tid >> 6;
                    #pragma unroll
                    for (int o = 0; o < ODIM; ++o) {
                        ld_hred[wv * 18 + o]        = hqa[o];
                        ld_hred[wv * 18 + ODIM + o] = hqb[o];
                    }
                }
                __syncthreads();
                if (tid < 18) {
                    float s = headb[tid % ODIM];
                    #pragma unroll
                    for (int wv = 0; wv < 8; ++wv) s += ld_hred[wv * 18 + tid];
                    const int j = tid / ODIM, o = tid - j * ODIM;
                    out[((size_t)(2 * b + j) * TSTEPS + i) * ODIM + o] = sig32(s);
                }
                __syncthreads();
            }
        }
    }
}

extern "C" void kernel_launch(void* const* d_in, const int* in_sizes, int n_in,
                              void* d_out, int out_size, void* d_ws, size_t ws_size,
                              hipStream_t stream) {
    (void)in_sizes; (void)n_in; (void)d_ws; (void)ws_size; (void)out_size;
    const float* input_seq = (const float*)d_in[0];
    // d_in[1] = autoregressive_steps (scalar) -- T fixed at 63 by the model
    const float* in_W   = (const float*)d_in[2];
    const float* in_b   = (const float*)d_in[3];
    const float* Aarr   = (const float*)d_in[4];
    const float* Barr   = (const float*)d_in[5];
    const float* Carr   = (const float*)d_in[6];
    const float* Darr   = (const float*)d_in[7];
    const float* outW   = (const float*)d_in[8];
    const float* outb   = (const float*)d_in[9];
    const float* ln_g   = (const float*)d_in[10];
    const float* ln_b   = (const float*)d_in[11];
    const float* headW  = (const float*)d_in[12];
    const float* headb  = (const float*)d_in[13];
    float* out = (float*)d_out;

    // No workspace use: zero inter-WG communication in this design.
    s4_decode_kernel<<<NWG, NTHR, 0, stream>>>(
        input_seq, in_W, in_b, Aarr, Barr, Carr, Darr,
        outW, outb, ln_g, ln_b, headW, headb, out);
}

// Round 7
// 2382.813 us; speedup vs baseline: 3.2852x; 1.2206x over previous
//
#include <hip/hip_runtime.h>
#include <math.h>

// Problem constants (fixed by the reference)
#define HDIM   512
#define NDIM   16
#define SEQ    64
#define TSTEPS 63
#define BATCH  256
#define ODIM   9
#define NTHR   512
#define NWG    128   // 2 batches per WG

// R14: 2-batch weight amortization (R13 thesis) with a register plan that
// fits the empirical 128-VGPR ceiling. R13 post-mortem: persistent demand
// ~133 (states 64 + params 48 + consts 21) spilled read-only values ->
// FETCH 1.42GB (62KB/WG-blkstep of scratch re-reads), killing the test.
// R14 persistent = 70 regs: states 64 + {in_b,in_W x3, ctx x2}. Params:
//   blk1 A/B/C in LDS (96KB, one-time stage, as in R11);
//   blk0 A/B/C streamed from GLOBAL each blk-step (coalesced arr[tid+512k],
//     96KB/WG-blkstep, shared across WGs -> L2-resident);
//   outb/ln_g/ln_b/headW read from global at use (L2-hot, negligible).
// Matvec: R11's proven depth-4 prefetch + R7-style decorrelation (row-quarter
// permutation (rg+b)&3, rotated start (b&31)*4) so the 128 active CUs don't
// sweep identical weight lines in lockstep. Zero inter-WG communication
// (R9/R10 lesson: mailbox paths are container/XCD-mapping dependent).

typedef float f32x4 __attribute__((ext_vector_type(4)));

__device__ __forceinline__ float gelu_f32(float x) {
    return 0.5f * x * (1.0f + erff(x * 0.70710678118654752440f));
}

__device__ __forceinline__ float sig32(float x) {
    return 1.0f / (1.0f + expf(-x));
}

__device__ __forceinline__ void fma_row4(float4& acc, const float4 g,
                                         const float4 w0, const float4 w1,
                                         const float4 w2, const float4 w3) {
    acc.x = fmaf(g.w, w3.x, fmaf(g.z, w2.x, fmaf(g.y, w1.x, fmaf(g.x, w0.x, acc.x))));
    acc.y = fmaf(g.w, w3.y, fmaf(g.z, w2.y, fmaf(g.y, w1.y, fmaf(g.x, w0.y, acc.y))));
    acc.z = fmaf(g.w, w3.z, fmaf(g.z, w2.z, fmaf(g.y, w1.z, fmaf(g.x, w0.z, acc.z))));
    acc.w = fmaf(g.w, w3.w, fmaf(g.z, w2.w, fmaf(g.y, w1.w, fmaf(g.x, w0.w, acc.w))));
}

// fold-exchange reduce over n (16 lanes, 16 values): lane n ends holding the
// full 16-lane sum of value v == n. Validated (passed) in R9/R10/R13 runs.
#define FOLD16(P, YOUT)                                                        \
    {                                                                          \
        float q8[8];                                                           \
        { const bool bt = (n & 1) != 0;                                        \
          _Pragma("unroll")                                                    \
          for (int u = 0; u < 8; ++u) {                                        \
              const float sd = bt ? P[2 * u] : P[2 * u + 1];                   \
              const float rc = __shfl_xor(sd, 1);                              \
              q8[u] = (bt ? P[2 * u + 1] : P[2 * u]) + rc;                     \
          } }                                                                  \
        float q4[4];                                                           \
        { const bool bt = (n & 2) != 0;                                        \
          _Pragma("unroll")                                                    \
          for (int u = 0; u < 4; ++u) {                                        \
              const float sd = bt ? q8[2 * u] : q8[2 * u + 1];                 \
              const float rc = __shfl_xor(sd, 2);                              \
              q4[u] = (bt ? q8[2 * u + 1] : q8[2 * u]) + rc;                   \
          } }                                                                  \
        float q2[2];                                                           \
        { const bool bt = (n & 4) != 0;                                        \
          _Pragma("unroll")                                                    \
          for (int u = 0; u < 2; ++u) {                                        \
              const float sd = bt ? q4[2 * u] : q4[2 * u + 1];                 \
              const float rc = __shfl_xor(sd, 4);                              \
              q2[u] = (bt ? q4[2 * u + 1] : q4[2 * u]) + rc;                   \
          } }                                                                  \
        { const bool bt = (n & 8) != 0;                                        \
          const float sd = bt ? q2[0] : q2[1];                                 \
          const float rc = __shfl_xor(sd, 8);                                  \
          YOUT = (bt ? q2[1] : q2[0]) + rc; }                                  \
    }

__global__ __launch_bounds__(NTHR, 1)
void s4_decode_kernel(
    const float* __restrict__ input_seq,   // (B,S,3)
    const float* __restrict__ in_W,        // (3,H)
    const float* __restrict__ in_b,        // (H)
    const float* __restrict__ Aarr,        // (L,H,N)
    const float* __restrict__ Barr,        // (L,H,N)
    const float* __restrict__ Carr,        // (L,H,N)
    const float* __restrict__ Darr,        // (L,H)
    const float* __restrict__ outW,        // (L,H,H)
    const float* __restrict__ outb,        // (L,H)
    const float* __restrict__ ln_g,        // (L,H)
    const float* __restrict__ ln_b,        // (L,H)
    const float* __restrict__ headW,       // (H,9)
    const float* __restrict__ headb,       // (9)
    float* __restrict__ out)               // (B,T,9)
{
    __shared__ __align__(16) float ld_x[2 * HDIM];      // block input, 2 batches
    __shared__ __align__(16) float ld_g[2 * HDIM];      // gelu out, 2 batches
    __shared__ __align__(16) float4 ld_z4[8 * 128];     // 16 KB matvec partials
    __shared__ __align__(16) float ld_A1[HDIM * NDIM];  // 32 KB blk1 params
    __shared__ __align__(16) float ld_B1[HDIM * NDIM];  // 32 KB
    __shared__ __align__(16) float ld_C1[HDIM * NDIM];  // 32 KB
    __shared__ float ld_D0[HDIM];
    __shared__ float ld_D1[HDIM];
    __shared__ float ld_red[32];                        // LN partials: 8 waves x 4
    __shared__ float ld_hred[8 * 2 * ODIM];             // head partials
    __shared__ float ld_logit[2 * ODIM];
    __shared__ float ld_dec[8];                         // 2 batches x {c0,c1,c2,pad}
    __shared__ int   ld_ptr[2];

    const int b   = blockIdx.x;            // WG id: batches 2b, 2b+1
    const int tid = threadIdx.x;
    const int n   = tid & 15;              // state n-index
    const int hg  = tid >> 4;              // [0,32) h sub-position

    // ---- stage blk1 A/B/C + D into LDS (one-time) ----
    for (int idx = tid; idx < HDIM * NDIM; idx += NTHR) {
        ld_A1[idx] = Aarr[HDIM * NDIM + idx];
        ld_B1[idx] = Barr[HDIM * NDIM + idx];
        ld_C1[idx] = Carr[HDIM * NDIM + idx];
    }
    ld_D0[tid] = Darr[tid];
    ld_D1[tid] = Darr[HDIM + tid];

    // ---- persistent: ONLY states (2 blks x 2 batches) + 6 scalars ----
    float s0a[16], s0b[16], s1a[16], s1b[16];
    #pragma unroll
    for (int k = 0; k < 16; ++k) { s0a[k] = 0.f; s0b[k] = 0.f; s1a[k] = 0.f; s1b[k] = 0.f; }

    const float inb_t = in_b[tid];
    const float w0 = in_W[tid], w1 = in_W[HDIM + tid], w2 = in_W[2 * HDIM + tid];
    float ctxa = 0.f, ctxb = 0.f;

    if (tid < 2) { ld_dec[4 * tid] = 0.f; ld_dec[4 * tid + 1] = 0.f; ld_dec[4 * tid + 2] = 1.f; }
    __syncthreads();

    for (int i = 0; i < TSTEPS; ++i) {
        // ---- decoder input projection, both batches, at own column ----
        const float dpa = fmaf(ld_dec[0], w0, fmaf(ld_dec[1], w1, fmaf(ld_dec[2], w2, inb_t)));
        const float dpb = fmaf(ld_dec[4], w0, fmaf(ld_dec[5], w1, fmaf(ld_dec[6], w2, inb_t)));
        __syncthreads();                    // ld_dec consumed
        ld_x[tid] = dpa;
        ld_x[HDIM + tid] = dpb;
        __syncthreads();

        float xna = 0.f, xnb = 0.f;

        #pragma unroll
        for (int blk = 0; blk < 2; ++blk) {
            // ---- S4 state update + C*s partials, both batches ----
            // blk0 params streamed from GLOBAL (coalesced, L2-resident);
            // blk1 params from LDS. Address: (hg+32k)*16+n == tid + 512k.
            float pa[16], pb[16];
            if (blk == 0) {
                #pragma unroll
                for (int k = 0; k < 16; ++k) {
                    const int h  = hg + 32 * k;
                    const int ia = tid + 512 * k;
                    const float Ak = Aarr[ia], Bk = Barr[ia], Ck = Carr[ia];
                    const float xa = ld_x[h], xb = ld_x[HDIM + h];
                    const float sva = fmaf(Ak, s0a[k], Bk * xa);
                    const float svb = fmaf(Ak, s0b[k], Bk * xb);
                    s0a[k] = sva; s0b[k] = svb;
                    pa[k] = sva * Ck;
                    pb[k] = svb * Ck;
                }
            } else {
                #pragma unroll
                for (int k = 0; k < 16; ++k) {
                    const int h  = hg + 32 * k;
                    const int ia = tid + 512 * k;
                    const float Ak = ld_A1[ia], Bk = ld_B1[ia], Ck = ld_C1[ia];
                    const float xa = ld_x[h], xb = ld_x[HDIM + h];
                    const float sva = fmaf(Ak, s1a[k], Bk * xa);
                    const float svb = fmaf(Ak, s1b[k], Bk * xb);
                    s1a[k] = sva; s1b[k] = svb;
                    pa[k] = sva * Ck;
                    pb[k] = svb * Ck;
                }
            }
            // ---- fold-exchange per batch; lane n writes h2 = hg + 32n ----
            {
                float ya, yb;
                FOLD16(pa, ya);
                FOLD16(pb, yb);
                const int h2 = hg + 32 * n;
                const float dd = blk ? ld_D1[h2] : ld_D0[h2];
                ld_g[h2]        = gelu_f32(fmaf(dd, ld_x[h2], ya));
                ld_g[HDIM + h2] = gelu_f32(fmaf(dd, ld_x[HDIM + h2], yb));
            }
            __syncthreads();

            // ---- matvec: 512 rows x 512 outputs x 2 batches ----
            // rows 4-way split; decorrelated sweep: quarter perm (rg+b)&3,
            // rotated start (b&31)*4 within the 128-row window.
            {
                const int rg   = tid >> 7;          // row quarter [0,4)
                const int c    = tid & 127;         // float4 output column
                const int rge  = (rg + b) & 3;
                const int rowbase = rge * 128;
                const int roff = (b & 31) * 4;      // 0..124, multiple of 4
                const float4* Wb = (const float4*)outW
                    + (((size_t)blk) << 16) + (size_t)rowbase * 128 + c;
                const float* gqa = &ld_g[rowbase];
                const float* gqb = &ld_g[HDIM + rowbase];
                float4 acca = make_float4(0.f, 0.f, 0.f, 0.f);
                float4 accb = make_float4(0.f, 0.f, 0.f, 0.f);
                int q = roff;
                float4 a0 = Wb[(size_t)(q + 0) * 128], a1 = Wb[(size_t)(q + 1) * 128],
                       a2 = Wb[(size_t)(q + 2) * 128], a3 = Wb[(size_t)(q + 3) * 128];
                #pragma unroll 2
                for (int ch = 0; ch < 32; ++ch) {
                    float4 b0, b1, b2, b3;
                    const int qn = (roff + 4 * ch + 4) & 127;
                    if (ch < 31) {
                        b0 = Wb[(size_t)(qn + 0) * 128];
                        b1 = Wb[(size_t)(qn + 1) * 128];
                        b2 = Wb[(size_t)(qn + 2) * 128];
                        b3 = Wb[(size_t)(qn + 3) * 128];
                    }
                    const float4 g4a = *(const float4*)&gqa[q];
                    const float4 g4b = *(const float4*)&gqb[q];
                    fma_row4(acca, g4a, a0, a1, a2, a3);
                    fma_row4(accb, g4b, a0, a1, a2, a3);
                    if (ch < 31) { a0 = b0; a1 = b1; a2 = b2; a3 = b3; q = qn; }
                }
                ld_z4[(0 * 4 + rg) * 128 + c] = acca;
                ld_z4[(1 * 4 + rg) * 128 + c] = accb;
            }
            __syncthreads();

            // ---- combine 4 row-quarter partials + residual + one-pass LN ----
            {
                const float* zf = (const float*)ld_z4;
                const float ob = outb[blk * HDIM + tid];        // L2-hot
                const float za = zf[0 * HDIM + tid] + zf[1 * HDIM + tid]
                               + zf[2 * HDIM + tid] + zf[3 * HDIM + tid] + ob;
                const float zb = zf[4 * HDIM + tid] + zf[5 * HDIM + tid]
                               + zf[6 * HDIM + tid] + zf[7 * HDIM + tid] + ob;
                const float ra = (i == 0) ? dpa : za;   // ref: residual=proj @ i==0
                const float rb = (i == 0) ? dpb : zb;
                const float ta = za + ra;
                const float tb = zb + rb;
                float v1a = ta, v2a = ta * ta, v1b = tb, v2b = tb * tb;
                #pragma unroll
                for (int m = 1; m < 64; m <<= 1) {
                    v1a += __shfl_xor(v1a, m);
                    v2a += __shfl_xor(v2a, m);
                    v1b += __shfl_xor(v1b, m);
                    v2b += __shfl_xor(v2b, m);
                }
                if ((tid & 63) == 0) {
                    const int wv = tid >> 6;
                    ld_red[wv * 4 + 0] = v1a; ld_red[wv * 4 + 1] = v2a;
                    ld_red[wv * 4 + 2] = v1b; ld_red[wv * 4 + 3] = v2b;
                }
                __syncthreads();
                float s1ra = 0.f, s2ra = 0.f, s1rb = 0.f, s2rb = 0.f;
                #pragma unroll
                for (int q2 = 0; q2 < 8; ++q2) {
                    s1ra += ld_red[q2 * 4 + 0]; s2ra += ld_red[q2 * 4 + 1];
                    s1rb += ld_red[q2 * 4 + 2]; s2rb += ld_red[q2 * 4 + 3];
                }
                const float glG = ln_g[blk * HDIM + tid];       // L2-hot
                const float glB = ln_b[blk * HDIM + tid];
                {
                    const float mu  = s1ra * (1.f / 512.f);
                    const float var = s2ra * (1.f / 512.f) - mu * mu;
                    xna = (ta - mu) * rsqrtf(var + 1e-5f) * glG + glB;
                }
                {
                    const float mu  = s1rb * (1.f / 512.f);
                    const float var = s2rb * (1.f / 512.f) - mu * mu;
                    xnb = (tb - mu) * rsqrtf(var + 1e-5f) * glG + glB;
                }
                if (blk == 0) {
                    __syncthreads();        // ld_red consumed before next-blk reuse
                    ld_x[tid] = xna;
                    ld_x[HDIM + tid] = xnb;
                    __syncthreads();
                }
            }
        } // blk

        // ================= head #1 (both batches) =================
        {
            const float va = xna + ctxa;
            const float vb = xnb + ctxb;
            float hpa[ODIM], hpb[ODIM];
            #pragma unroll
            for (int o = 0; o < ODIM; ++o) {
                const float w = headW[tid * ODIM + o];          // L2-hot
                hpa[o] = va * w; hpb[o] = vb * w;
            }
            #pragma unroll
            for (int m = 1; m < 64; m <<= 1) {
                #pragma unroll
                for (int o = 0; o < ODIM; ++o) {
                    hpa[o] += __shfl_xor(hpa[o], m);
                    hpb[o] += __shfl_xor(hpb[o], m);
                }
            }
            if ((tid & 63) == 0) {
                const int wv = tid >> 6;
                #pragma unroll
                for (int o = 0; o < ODIM; ++o) {
                    ld_hred[wv * 18 + o]        = hpa[o];
                    ld_hred[wv * 18 + ODIM + o] = hpb[o];
                }
            }
            __syncthreads();
            if (tid < 18) {
                float s = headb[tid % ODIM];
                #pragma unroll
                for (int wv = 0; wv < 8; ++wv) s += ld_hred[wv * 18 + tid];
                ld_logit[tid] = s;
            }
            __syncthreads();
        }

        const bool is_out = ((i & 1) == 0);
        if (is_out) {
            if (tid < 18) {
                const int j = tid / ODIM, o = tid - j * ODIM;
                out[((size_t)(2 * b + j) * TSTEPS + i) * ODIM + o] = sig32(ld_logit[tid]);
            }
            if (tid < 2) {
                const float nc = (sig32(ld_logit[tid * ODIM]) > 0.5f) ? 1.f : 0.f;
                ld_dec[4 * tid] = nc; ld_dec[4 * tid + 1] = 1.f; ld_dec[4 * tid + 2] = 0.f;
            }
            __syncthreads();
        } else {
            // np.argmax over f32 SIGMOIDS (saturation => not logit-argmax!)
            if (tid < 2) {
                const int base9 = tid * ODIM;
                int best = 0; float bv = sig32(ld_logit[base9 + 3]);
                #pragma unroll
                for (int o = 1; o < 6; ++o) {
                    const float v2 = sig32(ld_logit[base9 + 3 + o]);
                    if (v2 > bv) { bv = v2; best = o; }
                }
                ld_ptr[tid] = best;
                ld_dec[4 * tid] = 0.f; ld_dec[4 * tid + 1] = 0.f; ld_dec[4 * tid + 2] = 1.f;
            }
            __syncthreads();
            {   // ctx[j] += encoded[batch_j, ptr_j, :] at own column
                const float* ia = input_seq + ((size_t)(2 * b + 0) * SEQ + ld_ptr[0]) * 3;
                const float* ib = input_seq + ((size_t)(2 * b + 1) * SEQ + ld_ptr[1]) * 3;
                ctxa += fmaf(ia[0], w0, fmaf(ia[1], w1, fmaf(ia[2], w2, inb_t)));
                ctxb += fmaf(ib[0], w0, fmaf(ib[1], w1, fmaf(ib[2], w2, inb_t)));
            }
            __syncthreads();
            // ================= head #2 (post-ctx-update) =================
            {
                const float va = xna + ctxa;
                const float vb = xnb + ctxb;
                float hqa[ODIM], hqb[ODIM];
                #pragma unroll
                for (int o = 0; o < ODIM; ++o) {
                    const float w = headW[tid * ODIM + o];
                    hqa[o] = va * w; hqb[o] = vb * w;
                }
                #pragma unroll
                for (int m = 1; m < 64; m <<= 1) {
                    #pragma unroll
                    for (int o = 0; o < ODIM; ++o) {
                        hqa[o] += __shfl_xor(hqa[o], m);
                        hqb[o] += __shfl_xor(hqb[o], m);
                    }
                }
                if ((tid & 63) == 0) {
                    const int wv = tid >> 6;
                    #pragma unroll
                    for (int o = 0; o < ODIM; ++o) {
                        ld_hred[wv * 18 + o]        = hqa[o];
                        ld_hred[wv * 18 + ODIM + o] = hqb[o];
                    }
                }
                __syncthreads();
                if (tid < 18) {
                    float s = headb[tid % ODIM];
                    #pragma unroll
                    for (int wv = 0; wv < 8; ++wv) s += ld_hred[wv * 18 + tid];
                    const int j = tid / ODIM, o = tid - j * ODIM;
                    out[((size_t)(2 * b + j) * TSTEPS + i) * ODIM + o] = sig32(s);
                }
                __syncthreads();
            }
        }
    }
}

extern "C" void kernel_launch(void* const* d_in, const int* in_sizes, int n_in,
                              void* d_out, int out_size, void* d_ws, size_t ws_size,
                              hipStream_t stream) {
    (void)in_sizes; (void)n_in; (void)d_ws; (void)ws_size; (void)out_size;
    const float* input_seq = (const float*)d_in[0];
    // d_in[1] = autoregressive_steps (scalar) -- T fixed at 63 by the model
    const float* in_W   = (const float*)d_in[2];
    const float* in_b   = (const float*)d_in[3];
    const float* Aarr   = (const float*)d_in[4];
    const float* Barr   = (const float*)d_in[5];
    const float* Carr   = (const float*)d_in[6];
    const float* Darr   = (const float*)d_in[7];
    const float* outW   = (const float*)d_in[8];
    const float* outb   = (const float*)d_in[9];
    const float* ln_g   = (const float*)d_in[10];
    const float* ln_b   = (const float*)d_in[11];
    const float* headW  = (const float*)d_in[12];
    const float* headb  = (const float*)d_in[13];
    float* out = (float*)d_out;

    // No workspace use: zero inter-WG communication in this design.
    s4_decode_kernel<<<NWG, NTHR, 0, stream>>>(
        input_seq, in_W, in_b, Aarr, Barr, Carr, Darr,
        outW, outb, ln_g, ln_b, headW, headb, out);
}